// Round 1
// baseline (349.054 us; speedup 1.0000x reference)
//
#include <hip/hip_runtime.h>

// Problem constants (match reference)
#define B_ 128
#define NB_ 5
#define C_ 3
#define H_ 256
#define W_ 256

__global__ __launch_bounds__(256) void anomaly_kernel(
    const float4* __restrict__ images,       // [B,C,H,W] as float4
    const float4* __restrict__ blend_noise,  // [B,C,H,W] as float4
    const float*  __restrict__ beta_u,       // [B]
    const int*    __restrict__ centers_x,    // [B,NB]
    const int*    __restrict__ centers_y,    // [B,NB]
    const int*    __restrict__ radii,        // [B,NB]
    float4* __restrict__ aug_out,            // [B,C,H,W] as float4
    float4* __restrict__ mask_out)           // [B,1,H,W] as float4
{
    constexpr int HW4 = H_ * W_ / 4;            // 16384 float4 per (b,c) plane
    constexpr int BLOCKS_PER_B = HW4 / 256;     // 64 blocks per batch image

    // b is uniform across the block -> scalar loads for centers/radii/beta
    const int b    = blockIdx.x / BLOCKS_PER_B;
    const int pix4 = (blockIdx.x % BLOCKS_PER_B) * 256 + threadIdx.x;
    const int row  = pix4 >> 6;        // / (W/4 = 64)
    const int col4 = pix4 & 63;

    const float y  = (float)row;
    const float x0 = (float)(col4 * 4);

    // anomaly mask per pixel: inside any circle?
    // (blob_noise*0.5+0.5 in [0.5,1) > THRESH=0.3 always, so blob_noise is dead)
    bool am0 = false, am1 = false, am2 = false, am3 = false;
    #pragma unroll
    for (int nb = 0; nb < NB_; ++nb) {
        const float cx = (float)centers_x[b * NB_ + nb];
        const float cy = (float)centers_y[b * NB_ + nb];
        const float r  = (float)radii[b * NB_ + nb];
        const float r2 = r * r;
        const float dy = y - cy;
        const float dy2 = dy * dy;
        const float dx0 = x0 - cx;
        const float dx1 = x0 + 1.0f - cx;
        const float dx2 = x0 + 2.0f - cx;
        const float dx3 = x0 + 3.0f - cx;
        am0 = am0 || (dx0 * dx0 + dy2 <= r2);
        am1 = am1 || (dx1 * dx1 + dy2 <= r2);
        am2 = am2 || (dx2 * dx2 + dy2 <= r2);
        am3 = am3 || (dx3 * dx3 + dy2 <= r2);
    }

    // write anomaly mask
    float4 m;
    m.x = am0 ? 1.0f : 0.0f;
    m.y = am1 ? 1.0f : 0.0f;
    m.z = am2 ? 1.0f : 0.0f;
    m.w = am3 ? 1.0f : 0.0f;
    mask_out[b * HW4 + pix4] = m;

    const bool any_am = am0 || am1 || am2 || am3;
    const bool all_am = am0 && am1 && am2 && am3;

    const float beta = beta_u[b] * 0.9f + 0.1f;  // BETA_LO=0.1, BETA_HI=1.0

    #pragma unroll
    for (int c = 0; c < C_; ++c) {
        const int idx = (b * C_ + c) * HW4 + pix4;
        float4 img = make_float4(0.f, 0.f, 0.f, 0.f);
        float4 bln = make_float4(0.f, 0.f, 0.f, 0.f);
        if (!all_am) img = images[idx];       // needed where mask==0
        if (any_am)  bln = blend_noise[idx];  // needed where mask==1
        float4 o;
        o.x = am0 ? fminf(fmaxf(bln.x * beta, 0.f), 1.f) : fminf(fmaxf(img.x, 0.f), 1.f);
        o.y = am1 ? fminf(fmaxf(bln.y * beta, 0.f), 1.f) : fminf(fmaxf(img.y, 0.f), 1.f);
        o.z = am2 ? fminf(fmaxf(bln.z * beta, 0.f), 1.f) : fminf(fmaxf(img.z, 0.f), 1.f);
        o.w = am3 ? fminf(fmaxf(bln.w * beta, 0.f), 1.f) : fminf(fmaxf(img.w, 0.f), 1.f);
        aug_out[idx] = o;
    }
}

extern "C" void kernel_launch(void* const* d_in, const int* in_sizes, int n_in,
                              void* d_out, int out_size, void* d_ws, size_t ws_size,
                              hipStream_t stream) {
    const float* images      = (const float*)d_in[0];
    // d_in[1] = blob_noise — provably unused (see mask derivation above)
    const float* blend_noise = (const float*)d_in[2];
    const float* beta_u      = (const float*)d_in[3];
    const int*   centers_x   = (const int*)d_in[4];
    const int*   centers_y   = (const int*)d_in[5];
    const int*   radii       = (const int*)d_in[6];

    float* out   = (float*)d_out;
    float* aug   = out;                                        // B*C*H*W floats
    float* masks = out + (size_t)B_ * C_ * H_ * W_;            // B*H*W floats

    const int total_f4 = B_ * H_ * W_ / 4;   // 2,097,152 threads
    const int blocks = total_f4 / 256;       // 8192
    anomaly_kernel<<<blocks, 256, 0, stream>>>(
        (const float4*)images, (const float4*)blend_noise, beta_u,
        centers_x, centers_y, radii,
        (float4*)aug, (float4*)masks);
}

// Round 3
// 334.459 us; speedup vs baseline: 1.0436x; 1.0436x over previous
//
#include <hip/hip_runtime.h>

// Problem constants (match reference)
#define B_ 128
#define NB_ 5
#define C_ 3
#define H_ 256
#define W_ 256

// Native clang vector type — required by __builtin_nontemporal_load/store
// (HIP's float4 is a struct and is rejected).
typedef float fvec4 __attribute__((ext_vector_type(4)));

// All traffic is pure streaming (each byte touched exactly once), so use
// nontemporal loads/stores to keep the 256 MB L3 / 4 MB L2 out of the way.

__global__ __launch_bounds__(256) void anomaly_kernel(
    const fvec4* __restrict__ images,        // [B,C,H,W] as fvec4
    const fvec4* __restrict__ blend_noise,   // [B,C,H,W] as fvec4
    const float* __restrict__ beta_u,        // [B]
    const int*   __restrict__ centers_x,     // [B,NB]
    const int*   __restrict__ centers_y,     // [B,NB]
    const int*   __restrict__ radii,         // [B,NB]
    fvec4* __restrict__ aug_out,             // [B,C,H,W] as fvec4
    fvec4* __restrict__ mask_out)            // [B,1,H,W] as fvec4
{
    constexpr int HW4 = H_ * W_ / 4;            // 16384 fvec4 per (b,c) plane
    constexpr int BLOCKS_PER_B = HW4 / 256;     // 64 blocks per batch image

    // b is uniform across the block -> scalar loads for centers/radii/beta
    const int b    = blockIdx.x / BLOCKS_PER_B;
    const int pix4 = (blockIdx.x % BLOCKS_PER_B) * 256 + threadIdx.x;
    const int row  = pix4 >> 6;        // / (W/4 = 64)
    const int col4 = pix4 & 63;

    const float y  = (float)row;
    const float x0 = (float)(col4 * 4);

    // anomaly mask per pixel: inside any circle?
    // (blob_noise*0.5+0.5 in [0.5,1) > THRESH=0.3 always, so blob_noise is dead.
    //  dx,dy integers <=255 -> dx^2+dy^2 exact in fp32; sqrt monotone ->
    //  integer-squared compare matches the reference mask bit-for-bit.)
    bool am0 = false, am1 = false, am2 = false, am3 = false;
    #pragma unroll
    for (int nb = 0; nb < NB_; ++nb) {
        const float cx = (float)centers_x[b * NB_ + nb];
        const float cy = (float)centers_y[b * NB_ + nb];
        const float r  = (float)radii[b * NB_ + nb];
        const float r2 = r * r;
        const float dy = y - cy;
        const float dy2 = dy * dy;
        const float dx0 = x0 - cx;
        const float dx1 = x0 + 1.0f - cx;
        const float dx2 = x0 + 2.0f - cx;
        const float dx3 = x0 + 3.0f - cx;
        am0 = am0 || (dx0 * dx0 + dy2 <= r2);
        am1 = am1 || (dx1 * dx1 + dy2 <= r2);
        am2 = am2 || (dx2 * dx2 + dy2 <= r2);
        am3 = am3 || (dx3 * dx3 + dy2 <= r2);
    }

    // write anomaly mask (streaming store)
    fvec4 m;
    m.x = am0 ? 1.0f : 0.0f;
    m.y = am1 ? 1.0f : 0.0f;
    m.z = am2 ? 1.0f : 0.0f;
    m.w = am3 ? 1.0f : 0.0f;
    __builtin_nontemporal_store(m, &mask_out[b * HW4 + pix4]);

    const bool any_am = am0 || am1 || am2 || am3;
    const bool all_am = am0 && am1 && am2 && am3;

    const float beta = beta_u[b] * 0.9f + 0.1f;  // BETA_LO=0.1, BETA_HI=1.0

    #pragma unroll
    for (int c = 0; c < C_; ++c) {
        const int idx = (b * C_ + c) * HW4 + pix4;
        fvec4 img = (fvec4)0.0f;
        fvec4 bln = (fvec4)0.0f;
        if (!all_am) img = __builtin_nontemporal_load(&images[idx]);      // mask==0 pixels
        if (any_am)  bln = __builtin_nontemporal_load(&blend_noise[idx]); // mask==1 pixels
        fvec4 o;
        o.x = am0 ? fminf(fmaxf(bln.x * beta, 0.f), 1.f) : fminf(fmaxf(img.x, 0.f), 1.f);
        o.y = am1 ? fminf(fmaxf(bln.y * beta, 0.f), 1.f) : fminf(fmaxf(img.y, 0.f), 1.f);
        o.z = am2 ? fminf(fmaxf(bln.z * beta, 0.f), 1.f) : fminf(fmaxf(img.z, 0.f), 1.f);
        o.w = am3 ? fminf(fmaxf(bln.w * beta, 0.f), 1.f) : fminf(fmaxf(img.w, 0.f), 1.f);
        __builtin_nontemporal_store(o, &aug_out[idx]);
    }
}

extern "C" void kernel_launch(void* const* d_in, const int* in_sizes, int n_in,
                              void* d_out, int out_size, void* d_ws, size_t ws_size,
                              hipStream_t stream) {
    const float* images      = (const float*)d_in[0];
    // d_in[1] = blob_noise — provably unused (see mask derivation above)
    const float* blend_noise = (const float*)d_in[2];
    const float* beta_u      = (const float*)d_in[3];
    const int*   centers_x   = (const int*)d_in[4];
    const int*   centers_y   = (const int*)d_in[5];
    const int*   radii       = (const int*)d_in[6];

    float* out   = (float*)d_out;
    float* aug   = out;                                        // B*C*H*W floats
    float* masks = out + (size_t)B_ * C_ * H_ * W_;            // B*H*W floats

    const int total_f4 = B_ * H_ * W_ / 4;   // 2,097,152 threads
    const int blocks = total_f4 / 256;       // 8192
    anomaly_kernel<<<blocks, 256, 0, stream>>>(
        (const fvec4*)images, (const fvec4*)blend_noise, beta_u,
        centers_x, centers_y, radii,
        (fvec4*)aug, (fvec4*)masks);
}